// Round 10
// baseline (4260.628 us; speedup 1.0000x reference)
//
#include <hip/hip_runtime.h>
#include <hip/hip_bf16.h>

typedef __hip_bfloat16 bf16;
typedef __attribute__((ext_vector_type(8))) short bf16x8;
typedef __attribute__((ext_vector_type(4))) float f32x4;

#define HH 300     // hidden
#define NMOLS 2000
#define AFD 133    // atom feature dim
#define BFD 147    // bond feature dim
#define KP 480     // padded K of WT buffers (15 steps of 32)
#define GOFS 160   // tail region starts at k=160 (step 5)
#define NWT (320 * KP)   // elements per WT buffer

// ---- build WT[c][k] bf16: k<fd -> W0[k][c]; 160<=k<460 -> W1[k-160][c]; else 0 ----
// Zero pads load-bearing: tail reads overrun rows; products hit WT==0.
__global__ void build_wt(const float* __restrict__ W0, const float* __restrict__ W1,
                         int fd, bf16* __restrict__ WT)
{
  int idx = blockIdx.x * 256 + threadIdx.x;
  if (idx >= NWT) return;
  int c = idx / KP, k = idx - c * KP;
  float v = 0.f;
  if (c < HH) {
    if (k < fd) v = W0[(size_t)k * HH + c];
    else if (k >= GOFS && k < GOFS + HH) v = W1[(size_t)(k - GOFS) * HH + c];
  }
  WT[idx] = __float2bfloat16(v);
}

// ---- amsg[a][k] = sum_j msg[a2b[a][j]][k]; 8 elems/thread, 12 loads in flight ----
__global__ __launch_bounds__(256)
void gather6_k(const bf16* __restrict__ msg, const int* __restrict__ a2b,
               bf16* __restrict__ amsg, int A)
{
  int idx = blockIdx.x * 256 + threadIdx.x;
  if (idx >= A * 38) return;
  int a = idx / 38;
  int k8 = (idx - a * 38) * 8;           // 0,8,...,296 (last covers 4)
  const int* p = a2b + (size_t)a * 6;
  int pj[6];
#pragma unroll
  for (int j = 0; j < 6; j++) pj[j] = p[j];
  uint2 u0[6], u1[6];
#pragma unroll
  for (int j = 0; j < 6; j++) {
    const bf16* q = msg + (size_t)pj[j] * HH + k8;
    u0[j] = *(const uint2*)q;            // elems k8..k8+3
    u1[j] = *(const uint2*)(q + 4);      // elems k8+4..k8+7 (may cross row end; pad-safe, unused)
  }
  float s[8] = {0.f,0.f,0.f,0.f,0.f,0.f,0.f,0.f};
#pragma unroll
  for (int j = 0; j < 6; j++) {
    unsigned w[4] = {u0[j].x, u0[j].y, u1[j].x, u1[j].y};
#pragma unroll
    for (int q2 = 0; q2 < 4; q2++) {
      union { unsigned u; float f; } lo, hi;
      lo.u = w[q2] << 16;
      hi.u = w[q2] & 0xffff0000u;
      s[2 * q2]     += lo.f;
      s[2 * q2 + 1] += hi.f;
    }
  }
  short t[8];
#pragma unroll
  for (int j = 0; j < 8; j++) {
    union { bf16 b; short sh; } cv; cv.b = __float2bfloat16(s[j]); t[j] = cv.sh;
  }
  bf16* dst = amsg + (size_t)a * HH + k8;
  *(uint2*)dst = *(const uint2*)t;
  if (k8 + 8 <= HH) *(uint2*)((short*)dst + 4) = *(const uint2*)(t + 4);
}

// ============ paired-step pipelined MFMA GEMM: 64 rows x 320 cols, 4 waves split N ======
// K layout: steps 0..4 features (A0 f32, k<FD), steps 5..14 gathered tail bf16.
// Barrier every 2 steps (8 total); prefetch window 6 steps (register sets mod 6).
// MODE 0: C = f_bonds@Wi (5 steps);                 msg_out = relu(C), row0=0
// MODE 1: tail = amsg[b2a[r]] - msg[b2revb[r]];     msg_out = relu(C), row0=0
// MODE 2: tail = amsg[r];                           hid = relu(C + bias)
template<int MODE>
__global__ void gemm_q(const float* __restrict__ A0, const bf16* __restrict__ WT,
                       const int* __restrict__ b2a, const int* __restrict__ b2revb,
                       const bf16* __restrict__ amsg, const bf16* __restrict__ msgc,
                       const float* __restrict__ bias,
                       bf16* __restrict__ msg_out, float* __restrict__ hid_out, int M)
{
  constexpr int KSTEPS = (MODE == 0) ? 5 : 15;
  constexpr int FD = (MODE == 2) ? AFD : BFD;

  __shared__ __align__(16) short As[4][64 * 32];   // 4-deep ring, 4KB each

  const int tid = threadIdx.x;
  const int lane = tid & 63;
  const int wave = tid >> 6;
  const int gm0 = blockIdx.x * 64;

  // staging role: 4 threads per row, 8 bf16 (16B) per thread per step
  const int sr = tid >> 2;
  const int ss = tid & 3;
  const int arow = gm0 + sr;
  const bool rok = arow < M;
  const int crow = rok ? arow : 0;
  const int stoff = sr * 32 + (((ss ^ (sr >> 1)) & 3)) * 8;  // XOR-swizzled 16B slot

  int ba = 0, rb = 0;
  if (MODE == 1) { ba = b2a[crow]; rb = b2revb[crow]; }

  // compute role: A-frag LDS offsets (4 row tiles), B global base
  const int r = lane & 15;
  const int q = lane >> 4;
  int aoff[4];
#pragma unroll
  for (int i = 0; i < 4; i++) {
    int rr = i * 16 + r;
    aoff[i] = rr * 32 + ((q ^ (rr >> 1)) & 3) * 8;
  }
  const bf16* bb = WT + (size_t)(wave * 80 + r) * KP + q * 8;

  f32x4 acc[4][5];
#pragma unroll
  for (int i = 0; i < 4; i++)
#pragma unroll
    for (int j = 0; j < 5; j++) acc[i][j] = (f32x4){0.f, 0.f, 0.f, 0.f};

  // 6 in-flight register sets (prefetch window 6 steps); fully unrolled -> static idx
  float fv[6][8];
  uint2 ga[6][2], gb[6][2];

  auto issue = [&](int s) {
    const int set = s % 6;
    if (s < 5) {
      int kb = s * 32 + ss * 8;
#pragma unroll
      for (int j = 0; j < 8; j++) {
        int k = kb + j;
        fv[set][j] = (rok && k < FD) ? A0[(size_t)crow * FD + k] : 0.f;
      }
    } else {
      // tail reads may overrun the row by <=64B into the next row / region pad;
      // harmless: WT==0 for k past the real K. Region al() pads cover the last row.
      int kk = (s - 5) * 32 + ss * 8;
      if (MODE == 2) {
        const bf16* pa = amsg + (size_t)crow * HH + kk;
        ga[set][0] = *(const uint2*)pa;
        ga[set][1] = *(const uint2*)(pa + 4);
      } else {
        const bf16* pa = amsg + (size_t)ba * HH + kk;
        const bf16* pb = msgc + (size_t)rb * HH + kk;
        ga[set][0] = *(const uint2*)pa;
        ga[set][1] = *(const uint2*)(pa + 4);
        gb[set][0] = *(const uint2*)pb;
        gb[set][1] = *(const uint2*)(pb + 4);
      }
    }
  };

  auto finish = [&](int s) {
    const int set = s % 6;
    short* dst = &As[s & 3][stoff];
    if (s < 5) {
      bf16x8 t;
#pragma unroll
      for (int j = 0; j < 8; j++) {
        union { bf16 b; short sh; } cv; cv.b = __float2bfloat16(fv[set][j]); t[j] = cv.sh;
      }
      *(bf16x8*)dst = t;
    } else if (MODE == 2) {
      *(uint2*)dst = ga[set][0];
      *(uint2*)(dst + 4) = ga[set][1];
    } else {
      unsigned wa[4] = {ga[set][0].x, ga[set][0].y, ga[set][1].x, ga[set][1].y};
      unsigned wb[4] = {gb[set][0].x, gb[set][0].y, gb[set][1].x, gb[set][1].y};
      bf16x8 t;
#pragma unroll
      for (int q2 = 0; q2 < 4; q2++) {
        union { unsigned u; float f; } alo, ahi, blo, bhi;
        alo.u = wa[q2] << 16;         blo.u = wb[q2] << 16;
        ahi.u = wa[q2] & 0xffff0000u; bhi.u = wb[q2] & 0xffff0000u;
        union { bf16 b; short sh; } c0, c1;
        c0.b = __float2bfloat16(alo.f - blo.f);
        c1.b = __float2bfloat16(ahi.f - bhi.f);
        t[2 * q2] = c0.sh; t[2 * q2 + 1] = c1.sh;
      }
      *(bf16x8*)dst = t;
    }
  };

  auto compute = [&](int s) {
    const short* curb = &As[s & 3][0];
    bf16x8 af[4], bfr[5];
#pragma unroll
    for (int i = 0; i < 4; i++) af[i] = *(const bf16x8*)(curb + aoff[i]);
#pragma unroll
    for (int j = 0; j < 5; j++) bfr[j] = *(const bf16x8*)(bb + (size_t)j * 16 * KP + s * 32);
#pragma unroll
    for (int j = 0; j < 5; j++)
#pragma unroll
      for (int i = 0; i < 4; i++)
        acc[i][j] = __builtin_amdgcn_mfma_f32_16x16x32_bf16(af[i], bfr[j], acc[i][j], 0, 0, 0);
  };

  // ---- prologue: issue 6-step window, stage steps 0..1 ----
#pragma unroll
  for (int s = 0; s < 6; s++)
    if (s < KSTEPS) issue(s);
  finish(0);
  if (KSTEPS > 1) finish(1);
  asm volatile("s_waitcnt lgkmcnt(0)" ::: "memory");
  __builtin_amdgcn_s_barrier();

  // ---- main loop: barrier every 2 steps; prefetched loads in flight across it ----
#pragma unroll
  for (int s = 0; s < KSTEPS; s += 2) {
    if (s + 6 < KSTEPS) issue(s + 6);
    if (s + 7 < KSTEPS) issue(s + 7);
    compute(s);
    if (s + 1 < KSTEPS) compute(s + 1);
    if (s + 2 < KSTEPS) {
      finish(s + 2);
      if (s + 3 < KSTEPS) finish(s + 3);
      asm volatile("s_waitcnt lgkmcnt(0)" ::: "memory");
      __builtin_amdgcn_s_barrier();
    }
  }

  // ---- epilogue: C/D frag col=lane&15, row=(lane>>4)*4+reg ----
#pragma unroll
  for (int j = 0; j < 5; j++) {
    int c = wave * 80 + j * 16 + r;
    if (c >= HH) continue;
    float bia = (MODE == 2) ? bias[c] : 0.f;
#pragma unroll
    for (int i = 0; i < 4; i++) {
#pragma unroll
      for (int ri = 0; ri < 4; ri++) {
        int g = gm0 + i * 16 + q * 4 + ri;
        if (g >= M) continue;
        float v = acc[i][j][ri];
        if (MODE == 2) {
          hid_out[(size_t)g * HH + c] = fmaxf(v + bia, 0.f);
        } else {
          float rv = fmaxf(v, 0.f);
          if (g == 0) rv = 0.f;
          msg_out[(size_t)g * HH + c] = __float2bfloat16(rv);
        }
      }
    }
  }
}

// per-molecule mean over sorted mol_id (binary search, no atomics)
__global__ void readout_k(const float* __restrict__ hid, const int* __restrict__ mol_id,
                          float* __restrict__ out, int A)
{
  __shared__ int bnd[2];
  int m = blockIdx.x;
  if (threadIdx.x < 2) {
    int target = m + (int)threadIdx.x;
    int lo = 0, hi = A;
    while (lo < hi) { int mid = (lo + hi) >> 1; if (mol_id[mid] < target) lo = mid + 1; else hi = mid; }
    bnd[threadIdx.x] = lo;
  }
  __syncthreads();
  int s = bnd[0], e = bnd[1];
  int h = threadIdx.x;
  if (h >= HH) return;
  float acc = 0.f;
  for (int a = s; a < e; a++) acc += hid[(size_t)a * HH + h];
  int cnt = e - s; if (cnt < 1) cnt = 1;
  out[(size_t)m * HH + h] = acc / (float)cnt;
}

extern "C" void kernel_launch(void* const* d_in, const int* in_sizes, int n_in,
                              void* d_out, int out_size, void* d_ws, size_t ws_size,
                              hipStream_t stream)
{
  const float* f_atoms[2] = {(const float*)d_in[0], (const float*)d_in[2]};
  const float* f_bonds[2] = {(const float*)d_in[1], (const float*)d_in[3]};
  const float* W_i[2]     = {(const float*)d_in[4], (const float*)d_in[5]};
  const float* W_h[2]     = {(const float*)d_in[6], (const float*)d_in[7]};
  const float* W_o[2]     = {(const float*)d_in[8], (const float*)d_in[10]};
  const float* b_o[2]     = {(const float*)d_in[9], (const float*)d_in[11]};
  const int* a2b[2]    = {(const int*)d_in[12], (const int*)d_in[16]};
  const int* b2a[2]    = {(const int*)d_in[13], (const int*)d_in[17]};
  const int* b2revb[2] = {(const int*)d_in[14], (const int*)d_in[18]};
  const int* mol_id[2] = {(const int*)d_in[15], (const int*)d_in[19]};
  const int A = in_sizes[0] / AFD;   // 100001
  const int B = in_sizes[1] / BFD;   // 200001

  // ws: M0 bf16[B,H] | M1 bf16[B,H] / hid f32[A,H] overlay | amsg bf16[A,H] | 4x WT
  auto al = [](size_t x){ return (x + 255) & ~(size_t)255; };
  size_t r0 = al((size_t)B * HH * sizeof(bf16));
  size_t r1sz = (size_t)B * HH * sizeof(bf16);
  size_t hsz  = (size_t)A * HH * sizeof(float);
  size_t r1 = al(r1sz > hsz ? r1sz : hsz);
  size_t amsz = al((size_t)A * HH * sizeof(bf16));
  size_t wtsz = al((size_t)NWT * sizeof(bf16));
  if (ws_size < r0 + r1 + amsz + 4 * wtsz) return;  // proven available (round 5)

  char* ws = (char*)d_ws;
  bf16*  M0  = (bf16*)ws;
  bf16*  M1  = (bf16*)(ws + r0);
  float* hid = (float*)(ws + r0);
  bf16*  amsg = (bf16*)(ws + r0 + r1);
  size_t wofs = r0 + r1 + amsz;
  bf16* WT1[2] = {(bf16*)(ws + wofs),            (bf16*)(ws + wofs + wtsz)};
  bf16* WT2[2] = {(bf16*)(ws + wofs + 2 * wtsz), (bf16*)(ws + wofs + 3 * wtsz)};

  dim3 blk(256);
  dim3 gW((NWT + 255) / 256);
  dim3 gB((B + 63) / 64);
  dim3 gA((A + 63) / 64);
  dim3 gG((A * 38 + 255) / 256);

  for (int p = 0; p < 2; p++) {
    build_wt<<<gW, blk, 0, stream>>>(W_i[p], W_h[p], BFD, WT1[p]);
    build_wt<<<gW, blk, 0, stream>>>(W_o[p], W_o[p] + (size_t)AFD * HH, AFD, WT2[p]);
  }

  for (int p = 0; p < 2; p++) {
    float* out_p = (float*)d_out + (size_t)p * NMOLS * HH;
    // msg(M0) = relu(f_bonds @ W_i), row0=0
    gemm_q<0><<<gB, blk, 0, stream>>>(f_bonds[p], WT1[p], nullptr, nullptr,
                                      nullptr, nullptr, nullptr, M0, nullptr, B);
    // iteration 1: amsg = gather6(M0); M1 = relu(fb@Wi + (amsg[b2a]-M0[b2revb])@Wh)
    gather6_k<<<gG, blk, 0, stream>>>(M0, a2b[p], amsg, A);
    gemm_q<1><<<gB, blk, 0, stream>>>(f_bonds[p], WT1[p], b2a[p], b2revb[p],
                                      amsg, M0, nullptr, M1, nullptr, B);
    // iteration 2
    gather6_k<<<gG, blk, 0, stream>>>(M1, a2b[p], amsg, A);
    gemm_q<1><<<gB, blk, 0, stream>>>(f_bonds[p], WT1[p], b2a[p], b2revb[p],
                                      amsg, M1, nullptr, M0, nullptr, B);
    // output layer
    gather6_k<<<gG, blk, 0, stream>>>(M0, a2b[p], amsg, A);
    gemm_q<2><<<gA, blk, 0, stream>>>(f_atoms[p], WT2[p], nullptr, nullptr,
                                      amsg, nullptr, b_o[p], nullptr, hid, A);
    // per-molecule mean readout
    readout_k<<<NMOLS, 320, 0, stream>>>(hid, mol_id[p], out_p, A);
  }
}

// Round 11
// 1821.184 us; speedup vs baseline: 2.3395x; 2.3395x over previous
//
#include <hip/hip_runtime.h>
#include <hip/hip_bf16.h>

typedef __hip_bfloat16 bf16;
typedef __attribute__((ext_vector_type(8))) short bf16x8;
typedef __attribute__((ext_vector_type(4))) float f32x4;
typedef __attribute__((ext_vector_type(4))) int i32x4;

#define HH 300     // hidden
#define NMOLS 2000
#define AFD 133    // atom feature dim
#define BFD 147    // bond feature dim
#define KP 480     // padded K of WT buffers (15 steps of 32)
#define GOFS 160   // tail region starts at k=160 (step 5)
#define NWT (320 * KP)
#define FBP 160    // padded bf16 feature row length

// ---- direct global->LDS: dest = wave-uniform base + lane*16 ----
__device__ inline void gll16(short* lds_base, const void* gsrc) {
  auto l = (__attribute__((address_space(3))) short*)lds_base;
  auto g = (const __attribute__((address_space(1))) char*)gsrc;
  __builtin_amdgcn_global_load_lds(g, l, 16, 0, 0);
}

__device__ inline void vwait(int n) {   // folds to one literal asm under unroll
  switch (n) {
    case 5: asm volatile("s_waitcnt vmcnt(5)" ::: "memory"); break;
    case 6: asm volatile("s_waitcnt vmcnt(6)" ::: "memory"); break;
    default: asm volatile("s_waitcnt vmcnt(7)" ::: "memory"); break;
  }
}

// ---- build WT[c][k] bf16: k<fd -> W0[k][c]; 160<=k<460 -> W1[k-160][c]; else 0 ----
// Zero pads load-bearing: A-tail overruns rows; products hit WT==0.
__global__ void build_wt(const float* __restrict__ W0, const float* __restrict__ W1,
                         int fd, bf16* __restrict__ WT)
{
  int idx = blockIdx.x * 256 + threadIdx.x;
  if (idx >= NWT) return;
  int c = idx / KP, k = idx - c * KP;
  float v = 0.f;
  if (c < HH) {
    if (k < fd) v = W0[(size_t)k * HH + c];
    else if (k >= GOFS && k < GOFS + HH) v = W1[(size_t)(k - GOFS) * HH + c];
  }
  WT[idx] = __float2bfloat16(v);
}

// ---- pad/convert features: Y[r][0..159] = bf16(X[r][0..fd-1]) | zeros ----
__global__ __launch_bounds__(256)
void cvt_pad(const float* __restrict__ X, int fd, bf16* __restrict__ Y, int N)
{
  int idx = blockIdx.x * 256 + threadIdx.x;
  if (idx >= N * 20) return;
  int rr = idx / 20, c8 = (idx - rr * 20) * 8;
  short t[8];
#pragma unroll
  for (int j = 0; j < 8; j++) {
    int c = c8 + j;
    float v = (c < fd) ? X[(size_t)rr * fd + c] : 0.f;
    union { bf16 b; short s; } cv; cv.b = __float2bfloat16(v); t[j] = cv.s;
  }
  *(bf16x8*)(Y + (size_t)rr * FBP + c8) = *(const bf16x8*)t;
}

// ---- amsg[a][k] = sum_j msg[a2b[a][j]][k]; 8 elems/thread ----
__global__ __launch_bounds__(256)
void gather6_k(const bf16* __restrict__ msg, const int* __restrict__ a2b,
               bf16* __restrict__ amsg, int A)
{
  int idx = blockIdx.x * 256 + threadIdx.x;
  if (idx >= A * 38) return;
  int a = idx / 38;
  int k8 = (idx - a * 38) * 8;
  const int* p = a2b + (size_t)a * 6;
  uint2 u0[6], u1[6];
#pragma unroll
  for (int j = 0; j < 6; j++) {
    const bf16* q = msg + (size_t)p[j] * HH + k8;
    u0[j] = *(const uint2*)q;
    u1[j] = *(const uint2*)(q + 4);   // may cross row end; pad-safe, unused
  }
  float s[8] = {0.f,0.f,0.f,0.f,0.f,0.f,0.f,0.f};
#pragma unroll
  for (int j = 0; j < 6; j++) {
    unsigned w[4] = {u0[j].x, u0[j].y, u1[j].x, u1[j].y};
#pragma unroll
    for (int q2 = 0; q2 < 4; q2++) {
      union { unsigned u; float f; } lo, hi;
      lo.u = w[q2] << 16;
      hi.u = w[q2] & 0xffff0000u;
      s[2 * q2]     += lo.f;
      s[2 * q2 + 1] += hi.f;
    }
  }
  short t[8];
#pragma unroll
  for (int j = 0; j < 8; j++) {
    union { bf16 b; short sh; } cv; cv.b = __float2bfloat16(s[j]); t[j] = cv.sh;
  }
  bf16* dst = amsg + (size_t)a * HH + k8;
  *(uint2*)dst = *(const uint2*)t;
  if (k8 + 8 <= HH) *(uint2*)((short*)dst + 4) = *(const uint2*)(t + 4);
}

// ============ gll-staged MFMA GEMM: 64 rows x 320 cols, 4 waves split N ============
// All A-data is bf16 in global; staged via global_load_lds (no VGPR staging).
// Ring D=3; counted vmcnt (never 0); B-frags double-buffered in registers.
// MODE 0: C = fbb@Wi (5 steps);                          msg = relu(C), row0=0
// MODE 1: C = fbb@Wi + amsg[b2a]@Wh + (-msg[b2revb])@Wh; msg = relu(C), row0=0
// MODE 2: C = [fab | amsg]@Wo;                           hid = relu(C + bias)
template<int MODE>
__global__ __launch_bounds__(256)
void gemm_g(const bf16* __restrict__ FB, const bf16* __restrict__ WT,
            const int* __restrict__ b2a, const int* __restrict__ b2revb,
            const bf16* __restrict__ amsg, const bf16* __restrict__ msgc,
            const float* __restrict__ bias,
            bf16* __restrict__ msg_out, float* __restrict__ hid_out, int M)
{
  constexpr int KSTEPS = (MODE == 0) ? 5 : 15;
  constexpr bool DUAL = (MODE == 1);
  constexpr int D = 3;
  constexpr int G = DUAL ? 2 : 1;   // glls per step

  __shared__ __align__(16) short As[D][2048];           // 64 rows x 32 k per slot
  __shared__ __align__(16) short Ms[DUAL ? D : 1][2048];

  const int tid = threadIdx.x;
  const int lane = tid & 63;
  const int wave = tid >> 6;
  const int gm0 = blockIdx.x * 64;

  // staging map: lane -> (local row, swizzled source k-chunk). LDS dest is linear
  // (gll), swizzle applied on the SOURCE address; read side applies same XOR.
  const int lrow = wave * 16 + (lane >> 2);
  const int ssl = (lane & 3) ^ ((lrow >> 1) & 3);
  const int grow = min(gm0 + lrow, M - 1);   // clamped (stores guarded)
  int ba = 0, rb = 0;
  if constexpr (DUAL) { ba = b2a[grow]; rb = b2revb[grow]; }

  // compute map
  const int r = lane & 15, q = lane >> 4;
  int aoff[4];
#pragma unroll
  for (int i = 0; i < 4; i++) {
    int rr = i * 16 + r;
    aoff[i] = rr * 32 + ((q ^ (rr >> 1)) & 3) * 8;
  }
  const bf16* bb = WT + (size_t)(wave * 80 + r) * KP + q * 8;

  f32x4 acc[4][5];
#pragma unroll
  for (int i = 0; i < 4; i++)
#pragma unroll
    for (int j = 0; j < 5; j++) acc[i][j] = (f32x4){0.f, 0.f, 0.f, 0.f};

  bf16x8 bufB[2][5];
  auto issueB = [&](int s) {
#pragma unroll
    for (int j = 0; j < 5; j++)
      bufB[s & 1][j] = *(const bf16x8*)(bb + (size_t)j * 16 * KP + s * 32);
  };

  auto issueG = [&](int s) {
    short* la = &As[s % D][wave * 512];
    if constexpr (MODE == 0) {
      gll16(la, FB + (size_t)grow * FBP + s * 32 + ssl * 8);
    } else if constexpr (MODE == 2) {
      if (s < 5) gll16(la, FB + (size_t)grow * FBP + s * 32 + ssl * 8);
      else       gll16(la, amsg + (size_t)grow * HH + (s - 5) * 32 + ssl * 8);
    } else {
      short* lm = &Ms[s % D][wave * 512];
      if (s < 5) {
        const bf16* src = FB + (size_t)grow * FBP + s * 32 + ssl * 8;
        gll16(la, src);
        gll16(lm, src);   // duplicate: keeps vmcnt count uniform (2/step)
      } else {
        int kk = (s - 5) * 32 + ssl * 8;
        gll16(la, amsg + (size_t)ba * HH + kk);
        gll16(lm, msgc + (size_t)rb * HH + kk);
      }
    }
  };

  auto computeS = [&](int s) {
    const short* ca = &As[s % D][0];
    bf16x8 af[4];
#pragma unroll
    for (int i = 0; i < 4; i++) af[i] = *(const bf16x8*)(ca + aoff[i]);
    bf16x8 mfn[4];
    if constexpr (DUAL) {
      if (s >= 5) {
        const short* cm = &Ms[s % D][0];
#pragma unroll
        for (int i = 0; i < 4; i++) {
          union { bf16x8 h; i32x4 w; } u;
          u.h = *(const bf16x8*)(cm + aoff[i]);
          u.w = u.w ^ (int)0x80008000;    // bf16 sign-flip: (-msg)@Wh
          mfn[i] = u.h;
        }
      }
    }
#pragma unroll
    for (int j = 0; j < 5; j++)
#pragma unroll
      for (int i = 0; i < 4; i++) {
        acc[i][j] = __builtin_amdgcn_mfma_f32_16x16x32_bf16(af[i], bufB[s & 1][j], acc[i][j], 0, 0, 0);
        if constexpr (DUAL) {
          if (s >= 5)
            acc[i][j] = __builtin_amdgcn_mfma_f32_16x16x32_bf16(mfn[i], bufB[s & 1][j], acc[i][j], 0, 0, 0);
        }
      }
  };

  // ---- prologue: G(0), G(1), B(0)  (B after G: keeps ledger exact) ----
  issueG(0);
  issueG(1);
  issueB(0);
  __builtin_amdgcn_sched_barrier(0);

  // ---- main loop. Ledger: ops newer than G(s) = {B(s), G(s+1)} = 5+G,
  //      so vmcnt(5+G) guarantees this wave's step-s gll landed; barrier
  //      makes it block-wide. Last step: only B(s) newer -> vmcnt(5). ----
#pragma unroll
  for (int s = 0; s < KSTEPS; s++) {
    vwait(s == KSTEPS - 1 ? 5 : 5 + G);
    __builtin_amdgcn_s_barrier();
    __builtin_amdgcn_sched_barrier(0);
    if (s + 1 < KSTEPS) issueB(s + 1);
    if (s + 2 < KSTEPS) issueG(s + 2);
    __builtin_amdgcn_sched_barrier(0);
    computeS(s);
  }

  // ---- epilogue: C/D frag col=lane&15, row=(lane>>4)*4+reg ----
#pragma unroll
  for (int j = 0; j < 5; j++) {
    int c = wave * 80 + j * 16 + r;
    if (c >= HH) continue;
    float bia = (MODE == 2) ? bias[c] : 0.f;
#pragma unroll
    for (int i = 0; i < 4; i++) {
#pragma unroll
      for (int ri = 0; ri < 4; ri++) {
        int g = gm0 + i * 16 + q * 4 + ri;
        if (g >= M) continue;
        float v = acc[i][j][ri];
        if (MODE == 2) {
          hid_out[(size_t)g * HH + c] = fmaxf(v + bia, 0.f);
        } else {
          float rv = fmaxf(v, 0.f);
          if (g == 0) rv = 0.f;
          msg_out[(size_t)g * HH + c] = __float2bfloat16(rv);
        }
      }
    }
  }
}

// per-molecule mean over sorted mol_id (binary search, no atomics)
__global__ void readout_k(const float* __restrict__ hid, const int* __restrict__ mol_id,
                          float* __restrict__ out, int A)
{
  __shared__ int bnd[2];
  int m = blockIdx.x;
  if (threadIdx.x < 2) {
    int target = m + (int)threadIdx.x;
    int lo = 0, hi = A;
    while (lo < hi) { int mid = (lo + hi) >> 1; if (mol_id[mid] < target) lo = mid + 1; else hi = mid; }
    bnd[threadIdx.x] = lo;
  }
  __syncthreads();
  int s = bnd[0], e = bnd[1];
  int h = threadIdx.x;
  if (h >= HH) return;
  float acc = 0.f;
  for (int a = s; a < e; a++) acc += hid[(size_t)a * HH + h];
  int cnt = e - s; if (cnt < 1) cnt = 1;
  out[(size_t)m * HH + h] = acc / (float)cnt;
}

extern "C" void kernel_launch(void* const* d_in, const int* in_sizes, int n_in,
                              void* d_out, int out_size, void* d_ws, size_t ws_size,
                              hipStream_t stream)
{
  const float* f_atoms[2] = {(const float*)d_in[0], (const float*)d_in[2]};
  const float* f_bonds[2] = {(const float*)d_in[1], (const float*)d_in[3]};
  const float* W_i[2]     = {(const float*)d_in[4], (const float*)d_in[5]};
  const float* W_h[2]     = {(const float*)d_in[6], (const float*)d_in[7]};
  const float* W_o[2]     = {(const float*)d_in[8], (const float*)d_in[10]};
  const float* b_o[2]     = {(const float*)d_in[9], (const float*)d_in[11]};
  const int* a2b[2]    = {(const int*)d_in[12], (const int*)d_in[16]};
  const int* b2a[2]    = {(const int*)d_in[13], (const int*)d_in[17]};
  const int* b2revb[2] = {(const int*)d_in[14], (const int*)d_in[18]};
  const int* mol_id[2] = {(const int*)d_in[15], (const int*)d_in[19]};
  const int A = in_sizes[0] / AFD;   // 100001
  const int B = in_sizes[1] / BFD;   // 200001

  // ws: M0 | M1/hid | amsg | fbb | fab | 4x WT   (~397 MB; r9 proved >=422 MB)
  auto al = [](size_t x){ return (x + 255) & ~(size_t)255; };
  size_t r0 = al((size_t)B * HH * sizeof(bf16));
  size_t r1sz = (size_t)B * HH * sizeof(bf16);
  size_t hsz  = (size_t)A * HH * sizeof(float);
  size_t r1 = al(r1sz > hsz ? r1sz : hsz);
  size_t amsz = al((size_t)A * HH * sizeof(bf16));
  size_t fbbsz = al((size_t)B * FBP * sizeof(bf16));
  size_t fabsz = al((size_t)A * FBP * sizeof(bf16));
  size_t wtsz = al((size_t)NWT * sizeof(bf16));
  if (ws_size < r0 + r1 + amsz + fbbsz + fabsz + 4 * wtsz) return;

  char* ws = (char*)d_ws;
  bf16*  M0  = (bf16*)ws;
  bf16*  M1  = (bf16*)(ws + r0);
  float* hid = (float*)(ws + r0);
  bf16*  amsg = (bf16*)(ws + r0 + r1);
  bf16*  fbb  = (bf16*)(ws + r0 + r1 + amsz);
  bf16*  fab  = (bf16*)(ws + r0 + r1 + amsz + fbbsz);
  size_t wofs = r0 + r1 + amsz + fbbsz + fabsz;
  bf16* WT1[2] = {(bf16*)(ws + wofs),            (bf16*)(ws + wofs + wtsz)};
  bf16* WT2[2] = {(bf16*)(ws + wofs + 2 * wtsz), (bf16*)(ws + wofs + 3 * wtsz)};

  dim3 blk(256);
  dim3 gW((NWT + 255) / 256);
  dim3 gB((B + 63) / 64);
  dim3 gA((A + 63) / 64);
  dim3 gG((A * 38 + 255) / 256);

  for (int p = 0; p < 2; p++) {
    build_wt<<<gW, blk, 0, stream>>>(W_i[p], W_h[p], BFD, WT1[p]);
    build_wt<<<gW, blk, 0, stream>>>(W_o[p], W_o[p] + (size_t)AFD * HH, AFD, WT2[p]);
  }

  for (int p = 0; p < 2; p++) {
    float* out_p = (float*)d_out + (size_t)p * NMOLS * HH;
    cvt_pad<<<(B * 20 + 255) / 256, blk, 0, stream>>>(f_bonds[p], BFD, fbb, B);
    cvt_pad<<<(A * 20 + 255) / 256, blk, 0, stream>>>(f_atoms[p], AFD, fab, A);
    // msg(M0) = relu(fbb @ W_i), row0=0
    gemm_g<0><<<gB, blk, 0, stream>>>(fbb, WT1[p], nullptr, nullptr,
                                      nullptr, nullptr, nullptr, M0, nullptr, B);
    // iter 1: amsg = gather6(M0); M1 = relu(fbb@Wi + amsg[b2a]@Wh - M0[b2revb]@Wh)
    gather6_k<<<gG, blk, 0, stream>>>(M0, a2b[p], amsg, A);
    gemm_g<1><<<gB, blk, 0, stream>>>(fbb, WT1[p], b2a[p], b2revb[p],
                                      amsg, M0, nullptr, M1, nullptr, B);
    // iter 2
    gather6_k<<<gG, blk, 0, stream>>>(M1, a2b[p], amsg, A);
    gemm_g<1><<<gB, blk, 0, stream>>>(fbb, WT1[p], b2a[p], b2revb[p],
                                      amsg, M1, nullptr, M0, nullptr, B);
    // output layer
    gather6_k<<<gG, blk, 0, stream>>>(M0, a2b[p], amsg, A);
    gemm_g<2><<<gA, blk, 0, stream>>>(fab, WT2[p], nullptr, nullptr,
                                      amsg, nullptr, b_o[p], nullptr, hid, A);
    // per-molecule mean readout
    readout_k<<<NMOLS, 320, 0, stream>>>(hid, mol_id[p], out_p, A);
  }
}